// Round 9
// baseline (239.117 us; speedup 1.0000x reference)
//
#include <hip/hip_runtime.h>
#include <hip/hip_bf16.h>
#include <math.h>

#define D_SSM 512
#define D_STATE 16
#define CKPT_BASE 511     // first index of level 9
#define N_CKPT 512        // nodes at level 9
#define MPAD 16384

typedef __attribute__((ext_vector_type(8))) short short8;
typedef __attribute__((ext_vector_type(4))) float floatx4;

__device__ __forceinline__ unsigned short f2bf(float f) {
    unsigned int u = __float_as_uint(f);
    unsigned int r = (u + 0x7fffu + ((u >> 16) & 1u)) >> 16;
    return (unsigned short)r;
}
__device__ __forceinline__ float bf2f(unsigned short u) {
    return __uint_as_float(((unsigned int)u) << 16);
}
__device__ __forceinline__ void g2lds16(const void* g, void* l) {
    __builtin_amdgcn_global_load_lds(
        (const __attribute__((address_space(1))) void*)g,
        (__attribute__((address_space(3))) void*)l, 16, 0, 0);
}

// packed powers: p[q] = {r^(2q+1), r^(2q+2)}, dependency depth 4
__device__ __forceinline__ void pw_powers2(float r, float2* p) {
    float r2 = r * r, r4 = r2 * r2, r8 = r4 * r4;
    p[0].x = r;            p[0].y = r2;
    p[1].x = p[0].x * r2;  p[1].y = p[0].y * r2;
    p[2].x = p[0].x * r4;  p[2].y = p[0].y * r4;
    p[3].x = p[1].x * r4;  p[3].y = p[1].y * r4;
    p[4].x = p[0].x * r8;  p[4].y = p[0].y * r8;
    p[5].x = p[1].x * r8;  p[5].y = p[1].y * r8;
    p[6].x = p[2].x * r8;  p[6].y = p[2].y * r8;
    p[7].x = p[3].x * r8;  p[7].y = p[3].y * r8;
}

// ---------------- prep: bf16 casts + A-matrix per-channel table (grid-stride rows) ----------------
__global__ __launch_bounds__(256) void prep_kernel(
    const float* __restrict__ s, const float* __restrict__ w,
    const float* __restrict__ W_in, const float* __restrict__ W_delta,
    const float* __restrict__ W_B, const float* __restrict__ W_C,
    const float* __restrict__ A_log,
    unsigned short* __restrict__ s_bf, float* __restrict__ lw,
    unsigned short* __restrict__ Win_bf, unsigned short* __restrict__ Wd_bf,
    float* __restrict__ As_tab, int* __restrict__ fast_tab,
    int Nn)
{
    const int b = blockIdx.x, t = threadIdx.x;
    if (b < 2048) {
        // 8 rows per block (16384 rows total)
        #pragma unroll
        for (int rr = 0; rr < 8; rr++) {
            int row = b * 8 + rr;
            unsigned int pack = 0;
            if (row < Nn) {
                float2 sv = *(const float2*)(s + (size_t)row * 512 + t * 2);
                pack = (unsigned int)f2bf(sv.x) | ((unsigned int)f2bf(sv.y) << 16);
            }
            *(unsigned int*)(s_bf + (size_t)row * 512 + t * 2) = pack;
            if (t == 0) lw[row] = (row < Nn) ? logf(w[row] + 1e-6f) : 0.f;
        }
    } else if (b < 2048 + 512) {
        int c = b - 2048;
        float a0 = W_in[(size_t)c * 513 + t * 2];
        float a1 = W_in[(size_t)c * 513 + t * 2 + 1];
        *(unsigned int*)(Win_bf + (size_t)c * 512 + t * 2) =
            (unsigned int)f2bf(a0) | ((unsigned int)f2bf(a1) << 16);
    } else if (b < 2048 + 1024) {
        int c = b - 2048 - 512;
        float2 wv = *(const float2*)(W_delta + (size_t)c * 512 + t * 2);
        *(unsigned int*)(Wd_bf + (size_t)c * 512 + t * 2) =
            (unsigned int)f2bf(wv.x) | ((unsigned int)f2bf(wv.y) << 16);
    } else if (b < 2048 + 1024 + 128) {
        // rows 512..639 of W2: 0..15 = W_B, 16..31 = W_C, rest zero padding
        int c = b - 2048 - 1024;   // 0..127
        float2 wv; wv.x = 0.f; wv.y = 0.f;
        if (c < 16)      wv = *(const float2*)(W_B + (size_t)c * 512 + t * 2);
        else if (c < 32) wv = *(const float2*)(W_C + (size_t)(c - 16) * 512 + t * 2);
        *(unsigned int*)(Wd_bf + (size_t)(512 + c) * 512 + t * 2) =
            (unsigned int)f2bf(wv.x) | ((unsigned int)f2bf(wv.y) << 16);
    } else {
        // per-channel A table: As0 and geometric-series flag
        int ch = (b - (2048 + 1024 + 128)) * 256 + t;   // 0..511
        float As0 = -__expf(A_log[ch * 16]);
        bool ok = true;
        #pragma unroll
        for (int q = 1; q < 16; q++) {
            float As = -__expf(A_log[ch * 16 + q]);
            ok = ok && (fabsf(As - (float)(q + 1) * As0) <= 1e-4f * (float)(q + 1));
        }
        As_tab[ch] = As0;
        fast_tab[ch] = ok ? 1 : 0;
    }
}

// ---------------- bf16 MFMA GEMM, 128x128 tile (m97 structure), double-buffered LDS ----------------
__global__ __launch_bounds__(256) void gemm_mfma(
    const unsigned short* __restrict__ Abf,   // [16384][512] bf16
    const unsigned short* __restrict__ Wbf,   // [512 or 640][512] bf16
    float* __restrict__ outf,
    unsigned short* __restrict__ outbf,
    const float* __restrict__ bias,
    const float* __restrict__ lw,
    const float* __restrict__ wcol, int wcol_stride,
    const float* __restrict__ bw,
    const float* __restrict__ b_B, const float* __restrict__ b_C,
    float* __restrict__ Bm, float* __restrict__ Cm,
    int mode)
{
    __shared__ __align__(16) short As[2][128 * 32];   // 8 KB per buffer
    __shared__ __align__(16) short Bs[2][128 * 32];   // 8 KB per buffer
    const int tid = threadIdx.x;
    const int wave = tid >> 6, lane = tid & 63;

    // T1 chunked swizzle: valid because nwg (512 or 640) % 8 == 0
    const int nwg  = gridDim.x * gridDim.y;
    const int orig = blockIdx.y * gridDim.x + blockIdx.x;
    const int wsw  = (orig & 7) * (nwg >> 3) + (orig >> 3);
    const int bx   = wsw % gridDim.x;
    const int by   = wsw / gridDim.x;
    const int row0 = by * 128;
    const int col0 = bx * 128;

    const int wr = (wave >> 1) * 64;     // wave's 64-row strip
    const int wc = (wave & 1) * 64;      // wave's 64-col strip

    floatx4 acc[4][4] = {};

    const int srow = lane >> 2;                       // 0..15
    const int sg   = (lane & 3) ^ ((srow >> 1) & 3);  // XOR swizzle
    const int scol = sg * 8;

    const unsigned short* Ag = Abf + (size_t)(row0 + wave * 16 + srow) * 512 + scol;
    const unsigned short* Wg = Wbf + (size_t)(col0 + wave * 16 + srow) * 512 + scol;
    char* Al = (char*)&As[0][0] + wave * 1024;
    char* Bl = (char*)&Bs[0][0] + wave * 1024;

    #define STAGE(buf, k0)                                              \
        do {                                                            \
            g2lds16(Ag + (k0),            Al + (buf) * 8192);           \
            g2lds16(Ag + 64 * 512 + (k0), Al + (buf) * 8192 + 4096);    \
            g2lds16(Wg + (k0),            Bl + (buf) * 8192);           \
            g2lds16(Wg + 64 * 512 + (k0), Bl + (buf) * 8192 + 4096);    \
        } while (0)

    STAGE(0, 0);
    __syncthreads();

    for (int it = 0; it < 16; ++it) {
        const int cur = it & 1;
        if (it < 15) STAGE(cur ^ 1, (it + 1) * 32);

        short8 af[4], bfr[4];
        #pragma unroll
        for (int i = 0; i < 4; i++) {
            int m = wr + i * 16 + (lane & 15);
            int gm = (lane >> 4) ^ ((m >> 1) & 3);
            af[i] = *(const short8*)&As[cur][m * 32 + gm * 8];
        }
        #pragma unroll
        for (int j = 0; j < 4; j++) {
            int n = wc + j * 16 + (lane & 15);
            int gn = (lane >> 4) ^ ((n >> 1) & 3);
            bfr[j] = *(const short8*)&Bs[cur][n * 32 + gn * 8];
        }
        #pragma unroll
        for (int i = 0; i < 4; i++)
            #pragma unroll
            for (int j = 0; j < 4; j++)
                acc[i][j] = __builtin_amdgcn_mfma_f32_16x16x32_bf16(af[i], bfr[j], acc[i][j], 0, 0, 0);
        __syncthreads();   // drains prefetch vmcnt + guards buffer reuse
    }
    #undef STAGE

    // epilogue: C/D layout col=lane&15, row=(lane>>4)*4+reg
    if (col0 >= 512) {
        #pragma unroll
        for (int i = 0; i < 4; i++) {
            #pragma unroll
            for (int reg = 0; reg < 4; reg++) {
                int r = row0 + wr + i * 16 + (lane >> 4) * 4 + reg;
                #pragma unroll
                for (int j = 0; j < 4; j++) {
                    int c2 = wc + j * 16 + (lane & 15);   // 0..127 within tile
                    float z = acc[i][j][reg];
                    if (c2 < 16)      Bm[(size_t)r * 16 + c2]        = z + b_B[c2];
                    else if (c2 < 32) Cm[(size_t)r * 16 + (c2 - 16)] = z + b_C[c2 - 16];
                }
            }
        }
        return;
    }

    #pragma unroll
    for (int i = 0; i < 4; i++) {
        #pragma unroll
        for (int reg = 0; reg < 4; reg++) {
            int r = row0 + wr + i * 16 + (lane >> 4) * 4 + reg;
            float lwr = lw[r];
            #pragma unroll
            for (int j = 0; j < 4; j++) {
                int c = col0 + wc + j * 16 + (lane & 15);
                float z = acc[i][j][reg] + bias[c];
                if (mode == 0) {
                    float o = z + lwr * wcol[(size_t)c * wcol_stride];
                    outbf[(size_t)r * 512 + c] = f2bf(o);
                } else {
                    float sp = (z > 15.f) ? z : __logf(1.f + __expf(z));
                    float sg2 = __builtin_amdgcn_rcpf(1.f + __expf(-(lwr * wcol[c] + bw[c])));
                    outf[(size_t)r * 512 + c] = sp * sg2;
                }
            }
        }
    }
}

// ---------------- fused scan ----------------
// blocks 0..1023: deep — one block per (level-9 subtree p, level-10 branch c0).
//   NEW (r9): the 15 subtree-node (delta, x) rows are bulk-staged into LDS via
//   global_load_lds at block start (addresses are blockIdx-derived -> no dep
//   chain; ~46KB DMA per block, ~30MB in flight device-wide = BW-limited).
//   The 10-step ancestor walk runs with direct loads WHILE the DMA flies.
//   LN is done immediately per node (block reduction, alternating red banks)
//   so no Yb row buffer is needed -> LDS 46.2KB -> 3 blocks/CU.
// blocks 1024..1534: shallow nodes 0..510 (unchanged).
__global__ __launch_bounds__(512) void scan_fused(
    const unsigned short* __restrict__ x_bf, const float* __restrict__ delta,
    const float* __restrict__ Bm, const float* __restrict__ Cm,
    const float* __restrict__ A_log, const float* __restrict__ Dv,
    const float* __restrict__ gamma, const float* __restrict__ beta,
    const float* __restrict__ As_tab, const int* __restrict__ fast_tab,
    float* __restrict__ out)
{
    __shared__ __align__(16) char SMEMRAW[15 * 512 * 4 + 15 * 512 * 2 + 32 * 4];
    float* const DL  = (float*)SMEMRAW;                         // [15][512] fp32
    unsigned short* const XL = (unsigned short*)(SMEMRAW + 30720);  // [15][512] bf16
    float* const red = (float*)(SMEMRAW + 46080);               // [32]
    const int bid = blockIdx.x;
    const int d = threadIdx.x;
    const int wid = d >> 6, lane = d & 63;

    const float As0 = As_tab[d];
    const bool fast = fast_tab[d] != 0;
    const float dvd = Dv[d];

    if (bid < 2 * N_CKPT) {
        // ================= DEEP path (half-subtree per block) =================
        const int p  = bid & 511;
        const int c0 = bid >> 9;
        const int a9 = CKPT_BASE + p;
        const int n10 = 2 * a9 + 1 + c0;
        const float gm = gamma[d], bt = beta[d];

        // ---- issue bulk DMA: 15 subtree rows (BFS order, root=n10) ----
        // delta: 30 segments of 1KB; x: 15 segments of 1KB
        for (int i = wid; i < 30; i += 8) {
            int row = i >> 1, half = i & 1;
            int v = row + 1;
            int j = 31 - __builtin_clz((unsigned)v);
            int node = ((n10 + 1) << j) - 1 + (v - (1 << j));
            g2lds16(delta + (size_t)node * 512 + half * 256 + lane * 4,
                    (char*)DL + row * 2048 + half * 1024);
        }
        for (int i = wid; i < 15; i += 8) {
            int v = i + 1;
            int j = 31 - __builtin_clz((unsigned)v);
            int node = ((n10 + 1) << j) - 1 + (v - (1 << j));
            g2lds16(x_bf + (size_t)node * 512 + lane * 8,
                    (char*)XL + i * 1024);
        }

        // ---- ancestor walk (direct loads; overlaps the DMA) ----
        float2 H9[8];
        #pragma unroll
        for (int q = 0; q < 8; q++) { H9[q].x = 0.f; H9[q].y = 0.f; }
        float xv0 = 0.f;
        {
            float cum = 0.f;
            int a = a9;
            #pragma unroll
            for (int k = 0; k < 10; k++) {
                float da = delta[(size_t)a * 512 + d];
                float xv = bf2f(x_bf[(size_t)a * 512 + d]);
                if (k == 0) xv0 = xv;
                float bx = da * xv;
                const float2* B2 = (const float2*)(Bm + (size_t)a * 16);  // uniform s_load
                if (fast) {
                    float r = __expf(As0 * cum);
                    float2 pw2[8]; pw_powers2(r, pw2);
                    #pragma unroll
                    for (int q = 0; q < 8; q++) {
                        float2 bb = B2[q];
                        H9[q].x = fmaf(bx * pw2[q].x, bb.x, H9[q].x);
                        H9[q].y = fmaf(bx * pw2[q].y, bb.y, H9[q].y);
                    }
                } else {
                    const float* Bn = Bm + (size_t)a * 16;
                    #pragma unroll
                    for (int ss = 0; ss < 16; ss++) {
                        float As = -__expf(A_log[d * 16 + ss]);
                        float h = bx * __expf(As * cum) * Bn[ss];
                        if (ss & 1) H9[ss >> 1].y += h; else H9[ss >> 1].x += h;
                    }
                }
                cum += da;
                a = (a - 1) >> 1;
            }
        }
        __syncthreads();   // drains staging DMA (vmcnt 0) + publishes LDS

        int lncnt = 0;
        auto lnstore = [&](int n, float y) {
            float s1 = y, s2 = y * y;
            #pragma unroll
            for (int off = 32; off > 0; off >>= 1) {
                s1 += __shfl_xor(s1, off);
                s2 += __shfl_xor(s2, off);
            }
            int bank = (lncnt++ & 1) * 16;
            if (lane == 0) { red[bank + wid] = s1; red[bank + 8 + wid] = s2; }
            __syncthreads();
            float S1 = 0.f, S2 = 0.f;
            #pragma unroll
            for (int k = 0; k < 8; k++) { S1 += red[bank + k]; S2 += red[bank + 8 + k]; }
            float mu = S1 * (1.f / 512.f);
            float inv = rsqrtf(S2 * (1.f / 512.f) - mu * mu + 1e-5f);
            out[(size_t)n * 512 + d] = (y - mu) * inv * gm + bt;
        };

        // root row (a9 itself), only branch block c0==0
        if (c0 == 0) {
            const float2* C2 = (const float2*)(Cm + (size_t)a9 * 16);
            float y0 = 0.f, y1 = 0.f;
            #pragma unroll
            for (int q = 0; q < 8; q++) {
                float2 cc = C2[q];
                y0 = fmaf(cc.x, H9[q].x, y0);
                y1 = fmaf(cc.y, H9[q].y, y1);
            }
            lnstore(a9, fmaf(dvd, xv0, y0 + y1));
        }

        auto stepf = [&](int n, int row, const float2* Hp, float2* Hc) {
            float dlt = DL[row * 512 + d];
            float xv = bf2f(XL[row * 512 + d]);
            float bx = dlt * xv;
            const float2* B2 = (const float2*)(Bm + (size_t)n * 16);  // uniform
            const float2* C2 = (const float2*)(Cm + (size_t)n * 16);  // uniform
            float y0 = 0.f, y1 = 0.f;
            if (fast) {
                float r = __expf(As0 * dlt);
                float2 pw2[8]; pw_powers2(r, pw2);
                #pragma unroll
                for (int q = 0; q < 8; q++) {
                    float2 bb = B2[q], cc = C2[q];
                    float2 h;
                    h.x = fmaf(pw2[q].x, Hp[q].x, bx * bb.x);
                    h.y = fmaf(pw2[q].y, Hp[q].y, bx * bb.y);
                    Hc[q] = h;
                    y0 = fmaf(cc.x, h.x, y0);
                    y1 = fmaf(cc.y, h.y, y1);
                }
            } else {
                const float* Bn = Bm + (size_t)n * 16;
                const float* Cn = Cm + (size_t)n * 16;
                #pragma unroll
                for (int ss = 0; ss < 16; ss++) {
                    float Ab = __expf(dlt * (-__expf(A_log[d * 16 + ss])));
                    float hp = (ss & 1) ? Hp[ss >> 1].y : Hp[ss >> 1].x;
                    float h = fmaf(Ab, hp, bx * Bn[ss]);
                    if (ss & 1) Hc[ss >> 1].y = h; else Hc[ss >> 1].x = h;
                    y0 = fmaf(Cn[ss], h, y0);
                }
            }
            lnstore(n, fmaf(dvd, xv, y0 + y1));
        };

        float2 H10[8], H11[8], H12[8], H13[8];
        stepf(n10, 0, H9, H10);
        #pragma unroll
        for (int c1 = 0; c1 < 2; c1++) {
            int n11 = 2 * n10 + 1 + c1;
            stepf(n11, 1 + c1, H10, H11);
            #pragma unroll
            for (int c2 = 0; c2 < 2; c2++) {
                int n12 = 2 * n11 + 1 + c2;
                stepf(n12, 3 + 2 * c1 + c2, H11, H12);
                #pragma unroll
                for (int c3 = 0; c3 < 2; c3++) {
                    int n13 = 2 * n12 + 1 + c3;
                    stepf(n13, 7 + 4 * c1 + 2 * c2 + c3, H12, H13);
                }
            }
        }
    } else {
        // ================= SHALLOW path (node n, levels 0..8) =================
        const int n = bid - 2 * N_CKPT;

        float2 acc2[8];
        #pragma unroll
        for (int q = 0; q < 8; q++) { acc2[q].x = 0.f; acc2[q].y = 0.f; }

        float cum = 0.f;
        int a = n;
        #pragma unroll
        for (int k = 0; k < 9; k++) {
            if (a >= 0) {   // uniform branch
                float da = delta[(size_t)a * 512 + d];
                float bx = da * bf2f(x_bf[(size_t)a * 512 + d]);
                const float2* B2 = (const float2*)(Bm + (size_t)a * 16);  // uniform
                if (fast) {
                    float r = __expf(As0 * cum);
                    float2 pw2[8]; pw_powers2(r, pw2);
                    #pragma unroll
                    for (int q = 0; q < 8; q++) {
                        float2 bb = B2[q];
                        acc2[q].x = fmaf(bx * pw2[q].x, bb.x, acc2[q].x);
                        acc2[q].y = fmaf(bx * pw2[q].y, bb.y, acc2[q].y);
                    }
                } else {
                    const float* Bn = Bm + (size_t)a * 16;
                    #pragma unroll
                    for (int ss = 0; ss < 16; ss++) {
                        float As = -__expf(A_log[d * 16 + ss]);
                        float h = bx * __expf(As * cum) * Bn[ss];
                        if (ss & 1) acc2[ss >> 1].y += h; else acc2[ss >> 1].x += h;
                    }
                }
                cum += da;
                a = (a - 1) >> 1;
            }
        }

        float xv = bf2f(x_bf[(size_t)n * 512 + d]);
        const float2* C2 = (const float2*)(Cm + (size_t)n * 16);
        float y0 = 0.f, y1 = 0.f;
        #pragma unroll
        for (int q = 0; q < 8; q++) {
            float2 cc = C2[q];
            y0 = fmaf(cc.x, acc2[q].x, y0);
            y1 = fmaf(cc.y, acc2[q].y, y1);
        }
        float y = fmaf(dvd, xv, y0 + y1);

        float s1 = y, s2 = y * y;
        #pragma unroll
        for (int off = 32; off > 0; off >>= 1) {
            s1 += __shfl_xor(s1, off);
            s2 += __shfl_xor(s2, off);
        }
        if (lane == 0) { red[wid] = s1; red[wid + 8] = s2; }
        __syncthreads();
        float S1 = 0.f, S2 = 0.f;
        #pragma unroll
        for (int k = 0; k < 8; k++) { S1 += red[k]; S2 += red[k + 8]; }
        float mu = S1 * (1.f / 512.f);
        float var = S2 * (1.f / 512.f) - mu * mu;
        float inv = rsqrtf(var + 1e-5f);
        out[(size_t)n * 512 + d] = (y - mu) * inv * gamma[d] + beta[d];
    }
}

extern "C" void kernel_launch(void* const* d_in, const int* in_sizes, int n_in,
                              void* d_out, int out_size, void* d_ws, size_t ws_size,
                              hipStream_t stream) {
    const float* s_in   = (const float*)d_in[0];
    const float* w      = (const float*)d_in[1];
    const float* W_in    = (const float*)d_in[4];
    const float* b_in    = (const float*)d_in[5];
    const float* W_delta = (const float*)d_in[6];
    const float* b_delta = (const float*)d_in[7];
    const float* W_w     = (const float*)d_in[8];
    const float* b_w     = (const float*)d_in[9];
    const float* A_log   = (const float*)d_in[10];
    const float* Dv      = (const float*)d_in[11];
    const float* W_B     = (const float*)d_in[12];
    const float* b_B     = (const float*)d_in[13];
    const float* W_C     = (const float*)d_in[14];
    const float* b_C     = (const float*)d_in[15];
    const float* gamma   = (const float*)d_in[16];
    const float* beta    = (const float*)d_in[17];
    float* out = (float*)d_out;

    const int Nn = in_sizes[1];           // 16383

    float* ws    = (float*)d_ws;
    float* lw    = ws;                                      // 16384
    float* delta = lw + MPAD;                               // 16384*512 fp32
    float* Bm    = delta + (size_t)MPAD * 512;              // 16384*16
    float* Cm    = Bm + (size_t)MPAD * 16;                  // 16384*16
    unsigned short* s_bf  = (unsigned short*)(Cm + (size_t)MPAD * 16);  // 16384*512
    unsigned short* x_bf  = s_bf + (size_t)MPAD * 512;      // 16384*512
    unsigned short* Win_bf = x_bf + (size_t)MPAD * 512;     // 512*512
    unsigned short* Wd_bf  = Win_bf + 512 * 512;            // 640*512 (delta + B + C + pad)
    float* As_tab  = (float*)(Wd_bf + 640 * 512);           // 512
    int*   fast_tab = (int*)(As_tab + 512);                 // 512

    prep_kernel<<<2048 + 1024 + 128 + 2, 256, 0, stream>>>(
        s_in, w, W_in, W_delta, W_B, W_C, A_log,
        s_bf, lw, Win_bf, Wd_bf, As_tab, fast_tab, Nn);

    dim3 g1(4, 128);   // 128-col x 128-row tiles -> 512 blocks
    gemm_mfma<<<g1, 256, 0, stream>>>(s_bf, Win_bf, nullptr, x_bf,
                                      b_in, lw, W_in + 512, 513, nullptr,
                                      nullptr, nullptr, nullptr, nullptr, 0);
    dim3 g2(5, 128);   // 5th col tile = B/C columns
    gemm_mfma<<<g2, 256, 0, stream>>>(x_bf, Wd_bf, delta, nullptr,
                                      b_delta, lw, W_w, 1, b_w,
                                      b_B, b_C, Bm, Cm, 1);

    scan_fused<<<2 * N_CKPT + CKPT_BASE, 512, 0, stream>>>(
        x_bf, delta, Bm, Cm, A_log, Dv, gamma, beta, As_tab, fast_tab, out);
}

// Round 10
// 214.495 us; speedup vs baseline: 1.1148x; 1.1148x over previous
//
#include <hip/hip_runtime.h>
#include <hip/hip_bf16.h>
#include <math.h>

#define D_SSM 512
#define D_STATE 16
#define CKPT_BASE 511     // first index of level 9
#define N_CKPT 512        // nodes at level 9
#define MPAD 16384

typedef __attribute__((ext_vector_type(8))) short short8;
typedef __attribute__((ext_vector_type(4))) float floatx4;

__device__ __forceinline__ unsigned short f2bf(float f) {
    unsigned int u = __float_as_uint(f);
    unsigned int r = (u + 0x7fffu + ((u >> 16) & 1u)) >> 16;
    return (unsigned short)r;
}
__device__ __forceinline__ float bf2f(unsigned short u) {
    return __uint_as_float(((unsigned int)u) << 16);
}
__device__ __forceinline__ void g2lds16(const void* g, void* l) {
    __builtin_amdgcn_global_load_lds(
        (const __attribute__((address_space(1))) void*)g,
        (__attribute__((address_space(3))) void*)l, 16, 0, 0);
}

// r^(s+1) for s=0..15, dependency depth 4 instead of 16
__device__ __forceinline__ void pw_powers(float r, float* p) {
    float r2 = r * r, r4 = r2 * r2, r8 = r4 * r4;
    p[0] = r;          p[1] = r2;         p[2] = r2 * r;     p[3] = r4;
    p[4] = r4 * r;     p[5] = r4 * r2;    p[6] = r4 * p[2];  p[7] = r8;
    p[8] = r8 * r;     p[9] = r8 * r2;    p[10] = r8 * p[2]; p[11] = r8 * r4;
    p[12] = r8 * p[4]; p[13] = r8 * p[5]; p[14] = r8 * p[6]; p[15] = r8 * r8;
}

// ---------------- prep: bf16 casts + A-matrix per-channel table ----------------
__global__ __launch_bounds__(256) void prep_kernel(
    const float* __restrict__ s, const float* __restrict__ w,
    const float* __restrict__ W_in, const float* __restrict__ W_delta,
    const float* __restrict__ W_B, const float* __restrict__ W_C,
    const float* __restrict__ A_log,
    unsigned short* __restrict__ s_bf, float* __restrict__ lw,
    unsigned short* __restrict__ Win_bf, unsigned short* __restrict__ Wd_bf,
    float* __restrict__ As_tab, int* __restrict__ fast_tab,
    int Nn)
{
    const int b = blockIdx.x, t = threadIdx.x;
    if (b < MPAD) {
        unsigned int pack = 0;
        if (b < Nn) {
            float2 sv = *(const float2*)(s + (size_t)b * 512 + t * 2);
            pack = (unsigned int)f2bf(sv.x) | ((unsigned int)f2bf(sv.y) << 16);
        }
        *(unsigned int*)(s_bf + (size_t)b * 512 + t * 2) = pack;
        if (t == 0) lw[b] = (b < Nn) ? logf(w[b] + 1e-6f) : 0.f;
    } else if (b < MPAD + 512) {
        int c = b - MPAD;
        float a0 = W_in[(size_t)c * 513 + t * 2];
        float a1 = W_in[(size_t)c * 513 + t * 2 + 1];
        *(unsigned int*)(Win_bf + (size_t)c * 512 + t * 2) =
            (unsigned int)f2bf(a0) | ((unsigned int)f2bf(a1) << 16);
    } else if (b < MPAD + 1024) {
        int c = b - MPAD - 512;
        float2 wv = *(const float2*)(W_delta + (size_t)c * 512 + t * 2);
        *(unsigned int*)(Wd_bf + (size_t)c * 512 + t * 2) =
            (unsigned int)f2bf(wv.x) | ((unsigned int)f2bf(wv.y) << 16);
    } else if (b < MPAD + 1024 + 128) {
        // rows 512..639 of W2: 0..15 = W_B, 16..31 = W_C, rest zero padding
        int c = b - MPAD - 1024;   // 0..127
        float2 wv; wv.x = 0.f; wv.y = 0.f;
        if (c < 16)      wv = *(const float2*)(W_B + (size_t)c * 512 + t * 2);
        else if (c < 32) wv = *(const float2*)(W_C + (size_t)(c - 16) * 512 + t * 2);
        *(unsigned int*)(Wd_bf + (size_t)(512 + c) * 512 + t * 2) =
            (unsigned int)f2bf(wv.x) | ((unsigned int)f2bf(wv.y) << 16);
    } else {
        // per-channel A table: As0 and geometric-series flag
        int ch = (b - (MPAD + 1024 + 128)) * 256 + t;   // 0..511
        float As0 = -__expf(A_log[ch * 16]);
        bool ok = true;
        #pragma unroll
        for (int q = 1; q < 16; q++) {
            float As = -__expf(A_log[ch * 16 + q]);
            ok = ok && (fabsf(As - (float)(q + 1) * As0) <= 1e-4f * (float)(q + 1));
        }
        As_tab[ch] = As0;
        fast_tab[ch] = ok ? 1 : 0;
    }
}

// ---------------- bf16 MFMA GEMM, 128x128 tile (m97 structure), double-buffered LDS ----------------
__global__ __launch_bounds__(256) void gemm_mfma(
    const unsigned short* __restrict__ Abf,   // [16384][512] bf16
    const unsigned short* __restrict__ Wbf,   // [512 or 640][512] bf16
    float* __restrict__ outf,
    unsigned short* __restrict__ outbf,
    const float* __restrict__ bias,
    const float* __restrict__ lw,
    const float* __restrict__ wcol, int wcol_stride,
    const float* __restrict__ bw,
    const float* __restrict__ b_B, const float* __restrict__ b_C,
    float* __restrict__ Bm, float* __restrict__ Cm,
    int mode)
{
    __shared__ __align__(16) short As[2][128 * 32];   // 8 KB per buffer
    __shared__ __align__(16) short Bs[2][128 * 32];   // 8 KB per buffer
    const int tid = threadIdx.x;
    const int wave = tid >> 6, lane = tid & 63;

    // T1 chunked swizzle: valid because nwg (512 or 640) % 8 == 0
    const int nwg  = gridDim.x * gridDim.y;
    const int orig = blockIdx.y * gridDim.x + blockIdx.x;
    const int wsw  = (orig & 7) * (nwg >> 3) + (orig >> 3);
    const int bx   = wsw % gridDim.x;
    const int by   = wsw / gridDim.x;
    const int row0 = by * 128;
    const int col0 = bx * 128;

    const int wr = (wave >> 1) * 64;     // wave's 64-row strip
    const int wc = (wave & 1) * 64;      // wave's 64-col strip

    floatx4 acc[4][4] = {};

    const int srow = lane >> 2;                       // 0..15
    const int sg   = (lane & 3) ^ ((srow >> 1) & 3);  // XOR swizzle
    const int scol = sg * 8;

    const unsigned short* Ag = Abf + (size_t)(row0 + wave * 16 + srow) * 512 + scol;
    const unsigned short* Wg = Wbf + (size_t)(col0 + wave * 16 + srow) * 512 + scol;
    char* Al = (char*)&As[0][0] + wave * 1024;
    char* Bl = (char*)&Bs[0][0] + wave * 1024;

    #define STAGE(buf, k0)                                              \
        do {                                                            \
            g2lds16(Ag + (k0),            Al + (buf) * 8192);           \
            g2lds16(Ag + 64 * 512 + (k0), Al + (buf) * 8192 + 4096);    \
            g2lds16(Wg + (k0),            Bl + (buf) * 8192);           \
            g2lds16(Wg + 64 * 512 + (k0), Bl + (buf) * 8192 + 4096);    \
        } while (0)

    STAGE(0, 0);
    __syncthreads();

    for (int it = 0; it < 16; ++it) {
        const int cur = it & 1;
        if (it < 15) STAGE(cur ^ 1, (it + 1) * 32);

        short8 af[4], bfr[4];
        #pragma unroll
        for (int i = 0; i < 4; i++) {
            int m = wr + i * 16 + (lane & 15);
            int gm = (lane >> 4) ^ ((m >> 1) & 3);
            af[i] = *(const short8*)&As[cur][m * 32 + gm * 8];
        }
        #pragma unroll
        for (int j = 0; j < 4; j++) {
            int n = wc + j * 16 + (lane & 15);
            int gn = (lane >> 4) ^ ((n >> 1) & 3);
            bfr[j] = *(const short8*)&Bs[cur][n * 32 + gn * 8];
        }
        #pragma unroll
        for (int i = 0; i < 4; i++)
            #pragma unroll
            for (int j = 0; j < 4; j++)
                acc[i][j] = __builtin_amdgcn_mfma_f32_16x16x32_bf16(af[i], bfr[j], acc[i][j], 0, 0, 0);
        __syncthreads();   // drains prefetch vmcnt + guards buffer reuse
    }
    #undef STAGE

    // epilogue: C/D layout col=lane&15, row=(lane>>4)*4+reg
    if (col0 >= 512) {
        #pragma unroll
        for (int i = 0; i < 4; i++) {
            #pragma unroll
            for (int reg = 0; reg < 4; reg++) {
                int r = row0 + wr + i * 16 + (lane >> 4) * 4 + reg;
                #pragma unroll
                for (int j = 0; j < 4; j++) {
                    int c2 = wc + j * 16 + (lane & 15);   // 0..127 within tile
                    float z = acc[i][j][reg];
                    if (c2 < 16)      Bm[(size_t)r * 16 + c2]        = z + b_B[c2];
                    else if (c2 < 32) Cm[(size_t)r * 16 + (c2 - 16)] = z + b_C[c2 - 16];
                }
            }
        }
        return;
    }

    #pragma unroll
    for (int i = 0; i < 4; i++) {
        #pragma unroll
        for (int reg = 0; reg < 4; reg++) {
            int r = row0 + wr + i * 16 + (lane >> 4) * 4 + reg;
            float lwr = lw[r];
            #pragma unroll
            for (int j = 0; j < 4; j++) {
                int c = col0 + wc + j * 16 + (lane & 15);
                float z = acc[i][j][reg] + bias[c];
                if (mode == 0) {
                    float o = z + lwr * wcol[(size_t)c * wcol_stride];
                    outbf[(size_t)r * 512 + c] = f2bf(o);
                } else {
                    float sp = (z > 15.f) ? z : __logf(1.f + __expf(z));
                    float sg2 = __builtin_amdgcn_rcpf(1.f + __expf(-(lwr * wcol[c] + bw[c])));
                    outf[(size_t)r * 512 + c] = sp * sg2;
                }
            }
        }
    }
}

// ---------------- fused scan (r7 structure + depth-2 load pipeline) ----------------
// blocks 0..1023: deep — one block per (level-9 subtree p, level-10 branch c0).
// blocks 1024..1534: shallow nodes 0..510.
// NEW vs r7: the DFS's per-node (delta, x) loads are software-pipelined depth-2
// with named rotating registers (cd/nd1/nd2) — all node ids are affine in n10,
// so prefetch addresses have no data dependence. Same for the ancestor walk.
// +6 VGPR over r7's 56 (stays <=64 -> occupancy unchanged).
__global__ __launch_bounds__(512) void scan_fused(
    const unsigned short* __restrict__ x_bf, const float* __restrict__ delta,
    const float* __restrict__ Bm, const float* __restrict__ Cm,
    const float* __restrict__ A_log, const float* __restrict__ Dv,
    const float* __restrict__ gamma, const float* __restrict__ beta,
    const float* __restrict__ As_tab, const int* __restrict__ fast_tab,
    float* __restrict__ out)
{
    __shared__ __align__(16) float SMEM[16 * 512 + 31 * 32 + 10 * 16];  // 37.4 KB
    __shared__ int nid[16];
    const int bid = blockIdx.x;
    const int d = threadIdx.x;

    const float As0 = As_tab[d];
    const bool fast = fast_tab[d] != 0;
    const float dvd = Dv[d];

    if (bid < 2 * N_CKPT) {
        // ================= DEEP path (half-subtree per block) =================
        const int p  = bid & 511;
        const int c0 = bid >> 9;
        const int a9 = CKPT_BASE + p;
        float* const Yb   = SMEM;                 // [16][512]
        float* const BCs  = SMEM + 8192;          // [31][32]
        float* const Banc = SMEM + 8192 + 992;    // [10][16]

        // LDS preload of block-uniform B/C (issue first)
        for (int idx = d; idx < 31 * 32; idx += 512) {
            int i = idx >> 5, c = idx & 31;
            int v = i + 1;
            int j = 31 - __builtin_clz((unsigned)v);
            int node = ((a9 + 1) << j) - 1 + (v - (1 << j));
            BCs[i * 32 + c] = (c < 16) ? Bm[(size_t)node * 16 + c]
                                       : Cm[(size_t)node * 16 + (c - 16)];
        }
        if (d < 160) {
            int k = d >> 4, ss = d & 15;
            int a = a9;
            for (int q = 0; q < k; q++) a = (a - 1) >> 1;
            Banc[k * 16 + ss] = Bm[(size_t)a * 16 + ss];
        }

        // ---- early prefetch: first two DFS nodes + first two ancestors ----
        const int n10 = 2 * a9 + 1 + c0;
        float cd, nd1, nd2;
        unsigned short cx, nx1, nx2;
        cd  = delta[(size_t)n10 * 512 + d];
        cx  = x_bf[(size_t)n10 * 512 + d];
        nd1 = delta[(size_t)(2 * n10 + 1) * 512 + d];
        nx1 = x_bf[(size_t)(2 * n10 + 1) * 512 + d];

        int aB = (a9 - 1) >> 1;
        float adA = delta[(size_t)a9 * 512 + d];
        float adB = delta[(size_t)aB * 512 + d];
        unsigned short axA = x_bf[(size_t)a9 * 512 + d];
        unsigned short axB = x_bf[(size_t)aB * 512 + d];
        int anext = (aB - 1) >> 1;

        __syncthreads();

        // ---- ancestor walk: H at a9 (depth-2 pipelined loads) ----
        float H9v[16];
        #pragma unroll
        for (int ss = 0; ss < 16; ss++) H9v[ss] = 0.f;
        float xv0 = 0.f;
        {
            float cum = 0.f;
            #pragma unroll
            for (int k = 0; k < 10; k++) {
                float da = adA;
                float xvk = bf2f(axA);
                if (k == 0) xv0 = xvk;
                // rotate + prefetch ancestor k+2
                adA = adB; axA = axB;
                if (k < 8) {
                    adB = delta[(size_t)anext * 512 + d];
                    axB = x_bf[(size_t)anext * 512 + d];
                    anext = (anext - 1) >> 1;
                }
                float bx = da * xvk;
                if (fast) {
                    float r = __expf(As0 * cum);
                    float pw[16]; pw_powers(r, pw);
                    const floatx4* B4 = (const floatx4*)&Banc[k * 16];
                    #pragma unroll
                    for (int q = 0; q < 4; q++) {
                        floatx4 b = B4[q];
                        #pragma unroll
                        for (int u = 0; u < 4; u++) {
                            int ss = q * 4 + u;
                            H9v[ss] = fmaf(bx * pw[ss], b[u], H9v[ss]);
                        }
                    }
                } else {
                    #pragma unroll
                    for (int ss = 0; ss < 16; ss++) {
                        float As = -__expf(A_log[d * 16 + ss]);
                        H9v[ss] = fmaf(bx * __expf(As * cum), Banc[k * 16 + ss], H9v[ss]);
                    }
                }
                cum += da;
            }
        }

        auto stepf = [&](int n, int bfs, float dlt, unsigned short xraw,
                         const float* Hp, float* Hc, int slot) {
            float xv = bf2f(xraw);
            float bx = dlt * xv;
            const floatx4* B4 = (const floatx4*)&BCs[bfs * 32];
            const floatx4* C4 = (const floatx4*)&BCs[bfs * 32 + 16];
            float y0 = 0.f, y1 = 0.f;
            if (fast) {
                float r = __expf(As0 * dlt);
                float pw[16]; pw_powers(r, pw);
                #pragma unroll
                for (int q = 0; q < 4; q++) {
                    floatx4 b = B4[q], c = C4[q];
                    #pragma unroll
                    for (int u = 0; u < 4; u++) {
                        int ss = q * 4 + u;
                        Hc[ss] = fmaf(pw[ss], Hp[ss], bx * b[u]);
                        if (ss & 1) y1 = fmaf(c[u], Hc[ss], y1);
                        else        y0 = fmaf(c[u], Hc[ss], y0);
                    }
                }
            } else {
                #pragma unroll
                for (int ss = 0; ss < 16; ss++) {
                    float Ab = __expf(dlt * (-__expf(A_log[d * 16 + ss])));
                    Hc[ss] = fmaf(Ab, Hp[ss], bx * BCs[bfs * 32 + ss]);
                    float cc = BCs[bfs * 32 + 16 + ss];
                    if (ss & 1) y1 = fmaf(cc, Hc[ss], y1);
                    else        y0 = fmaf(cc, Hc[ss], y0);
                }
            }
            Yb[slot * 512 + d] = fmaf(dvd, xv, y0 + y1);
            if (d == 0) nid[slot] = n;
        };
        auto leaff = [&](int n, int bfs, float dlt, unsigned short xraw,
                         const float* Hp, int slot) {
            float xv = bf2f(xraw);
            float bx = dlt * xv;
            const floatx4* B4 = (const floatx4*)&BCs[bfs * 32];
            const floatx4* C4 = (const floatx4*)&BCs[bfs * 32 + 16];
            float y0 = 0.f, y1 = 0.f;
            if (fast) {
                float r = __expf(As0 * dlt);
                float pw[16]; pw_powers(r, pw);
                #pragma unroll
                for (int q = 0; q < 4; q++) {
                    floatx4 b = B4[q], c = C4[q];
                    #pragma unroll
                    for (int u = 0; u < 4; u++) {
                        int ss = q * 4 + u;
                        float h = fmaf(pw[ss], Hp[ss], bx * b[u]);
                        if (ss & 1) y1 = fmaf(c[u], h, y1);
                        else        y0 = fmaf(c[u], h, y0);
                    }
                }
            } else {
                #pragma unroll
                for (int ss = 0; ss < 16; ss++) {
                    float Ab = __expf(dlt * (-__expf(A_log[d * 16 + ss])));
                    float h = fmaf(Ab, Hp[ss], bx * BCs[bfs * 32 + ss]);
                    float cc = BCs[bfs * 32 + 16 + ss];
                    if (ss & 1) y1 = fmaf(cc, h, y1);
                    else        y0 = fmaf(cc, h, y0);
                }
            }
            Yb[slot * 512 + d] = fmaf(dvd, xv, y0 + y1);
            if (d == 0) nid[slot] = n;
        };

        int slot = 0;
        if (c0 == 0) {
            // root row (a9 itself) — x captured during the walk
            const floatx4* C4 = (const floatx4*)&BCs[16];
            float y0 = 0.f, y1 = 0.f;
            #pragma unroll
            for (int q = 0; q < 4; q++) {
                floatx4 c = C4[q];
                #pragma unroll
                for (int u = 0; u < 4; u++) {
                    int ss = q * 4 + u;
                    if (ss & 1) y1 = fmaf(c[u], H9v[ss], y1);
                    else        y0 = fmaf(c[u], H9v[ss], y0);
                }
            }
            Yb[d] = fmaf(dvd, xv0, y0 + y1);
            if (d == 0) nid[0] = a9;
            slot = 1;
        }

        float H10[16], H11[16], H12[16];
        // depth-2 pipelined DFS: prefetch node i+2, compute node i, rotate.
        #define PREF(NODE) do { nd2 = delta[(size_t)(NODE) * 512 + d]; \
                                nx2 = x_bf[(size_t)(NODE) * 512 + d]; } while (0)
        #define ROT() do { cd = nd1; cx = nx1; nd1 = nd2; nx1 = nx2; } while (0)
        PREF(4 * n10 + 3);   stepf(n10,          1 + c0,   cd, cx, H9v, H10, slot++); ROT();
        PREF(8 * n10 + 7);   stepf(2 * n10 + 1,  3 + 2*c0, cd, cx, H10, H11, slot++); ROT();
        PREF(8 * n10 + 8);   stepf(4 * n10 + 3,  7 + 4*c0, cd, cx, H11, H12, slot++); ROT();
        PREF(4 * n10 + 4);   leaff(8 * n10 + 7,  15 + 8*c0, cd, cx, H12, slot++); ROT();
        PREF(8 * n10 + 9);   leaff(8 * n10 + 8,  16 + 8*c0, cd, cx, H12, slot++); ROT();
        PREF(8 * n10 + 10);  stepf(4 * n10 + 4,  8 + 4*c0, cd, cx, H11, H12, slot++); ROT();
        PREF(2 * n10 + 2);   leaff(8 * n10 + 9,  17 + 8*c0, cd, cx, H12, slot++); ROT();
        PREF(4 * n10 + 5);   leaff(8 * n10 + 10, 18 + 8*c0, cd, cx, H12, slot++); ROT();
        PREF(8 * n10 + 11);  stepf(2 * n10 + 2,  4 + 2*c0, cd, cx, H10, H11, slot++); ROT();
        PREF(8 * n10 + 12);  stepf(4 * n10 + 5,  9 + 4*c0, cd, cx, H11, H12, slot++); ROT();
        PREF(4 * n10 + 6);   leaff(8 * n10 + 11, 19 + 8*c0, cd, cx, H12, slot++); ROT();
        PREF(8 * n10 + 13);  leaff(8 * n10 + 12, 20 + 8*c0, cd, cx, H12, slot++); ROT();
        PREF(8 * n10 + 14);  stepf(4 * n10 + 6,  10 + 4*c0, cd, cx, H11, H12, slot++); ROT();
                             leaff(8 * n10 + 13, 21 + 8*c0, cd, cx, H12, slot++); ROT();
                             leaff(8 * n10 + 14, 22 + 8*c0, cd, cx, H12, slot++);
        #undef PREF
        #undef ROT
        __syncthreads();

        // LN + store: 16 rows (c0=0) or 15 rows (c0=1)
        const int cnt = (c0 == 0) ? 16 : 15;
        const int w = d >> 6, lane = d & 63;
        for (int i = w; i < cnt; i += 8) {
            int n = nid[i];
            float v[8]; float s1 = 0.f, s2 = 0.f;
            #pragma unroll
            for (int k = 0; k < 8; k++) {
                v[k] = Yb[i * 512 + lane + 64 * k];
                s1 += v[k]; s2 += v[k] * v[k];
            }
            #pragma unroll
            for (int off = 32; off > 0; off >>= 1) {
                s1 += __shfl_xor(s1, off);
                s2 += __shfl_xor(s2, off);
            }
            float mu = s1 * (1.f / 512.f);
            float inv = rsqrtf(s2 * (1.f / 512.f) - mu * mu + 1e-5f);
            #pragma unroll
            for (int k = 0; k < 8; k++) {
                int ch = lane + 64 * k;
                out[(size_t)n * 512 + ch] = (v[k] - mu) * inv * gamma[ch] + beta[ch];
            }
        }
    } else {
        // ================= SHALLOW path (node n, levels 0..8) =================
        const int n = bid - 2 * N_CKPT;
        float* const Banc9 = SMEM;          // [9][16]
        float* const Cn    = SMEM + 144;    // [16]
        float* const red   = SMEM + 160;    // [16]

        if (d < 144) {
            int k = d >> 4, ss = d & 15;
            int a = n;
            for (int q = 0; q < 9; q++) if (q < k) a = (a < 0) ? -1 : ((a - 1) >> 1);
            Banc9[k * 16 + ss] = (a >= 0) ? Bm[(size_t)a * 16 + ss] : 0.f;
        }
        if (d >= 240 && d < 256) Cn[d - 240] = Cm[(size_t)n * 16 + (d - 240)];

        // prefetch (zero-filled past the root: zero bx is a no-op in the scan)
        float adl[9]; unsigned short axr[9];
        {
            int a = n;
            #pragma unroll
            for (int k = 0; k < 9; k++) {
                bool v = a >= 0;
                adl[k] = v ? delta[(size_t)a * 512 + d] : 0.f;
                axr[k] = v ? x_bf[(size_t)a * 512 + d] : (unsigned short)0;
                a = v ? ((a - 1) >> 1) : -1;
            }
        }
        __syncthreads();

        float acc[16];
        #pragma unroll
        for (int ss = 0; ss < 16; ss++) acc[ss] = 0.f;

        float cum = 0.f;
        #pragma unroll
        for (int k = 0; k < 9; k++) {
            float da = adl[k];
            float bx = da * bf2f(axr[k]);
            if (fast) {
                float r = __expf(As0 * cum);
                float pw[16]; pw_powers(r, pw);
                const floatx4* B4 = (const floatx4*)&Banc9[k * 16];
                #pragma unroll
                for (int q = 0; q < 4; q++) {
                    floatx4 b = B4[q];
                    #pragma unroll
                    for (int u = 0; u < 4; u++) {
                        int ss = q * 4 + u;
                        acc[ss] = fmaf(bx * pw[ss], b[u], acc[ss]);
                    }
                }
            } else {
                #pragma unroll
                for (int ss = 0; ss < 16; ss++) {
                    float As = -__expf(A_log[d * 16 + ss]);
                    acc[ss] = fmaf(bx * __expf(As * cum), Banc9[k * 16 + ss], acc[ss]);
                }
            }
            cum += da;
        }

        float xv = bf2f(axr[0]);
        float y0 = 0.f, y1 = 0.f;
        const floatx4* C4 = (const floatx4*)&Cn[0];
        #pragma unroll
        for (int q = 0; q < 4; q++) {
            floatx4 c = C4[q];
            #pragma unroll
            for (int u = 0; u < 4; u++) {
                int ss = q * 4 + u;
                if (ss & 1) y1 = fmaf(c[u], acc[ss], y1);
                else        y0 = fmaf(c[u], acc[ss], y0);
            }
        }
        float y = fmaf(dvd, xv, y0 + y1);

        float s1 = y, s2 = y * y;
        #pragma unroll
        for (int off = 32; off > 0; off >>= 1) {
            s1 += __shfl_xor(s1, off);
            s2 += __shfl_xor(s2, off);
        }
        int wid = d >> 6, lane = d & 63;
        if (lane == 0) { red[wid] = s1; red[wid + 8] = s2; }
        __syncthreads();
        float S1 = 0.f, S2 = 0.f;
        #pragma unroll
        for (int k = 0; k < 8; k++) { S1 += red[k]; S2 += red[k + 8]; }
        float mu = S1 * (1.f / 512.f);
        float var = S2 * (1.f / 512.f) - mu * mu;
        float inv = rsqrtf(var + 1e-5f);
        out[(size_t)n * 512 + d] = (y - mu) * inv * gamma[d] + beta[d];
    }
}

extern "C" void kernel_launch(void* const* d_in, const int* in_sizes, int n_in,
                              void* d_out, int out_size, void* d_ws, size_t ws_size,
                              hipStream_t stream) {
    const float* s_in   = (const float*)d_in[0];
    const float* w      = (const float*)d_in[1];
    const float* W_in    = (const float*)d_in[4];
    const float* b_in    = (const float*)d_in[5];
    const float* W_delta = (const float*)d_in[6];
    const float* b_delta = (const float*)d_in[7];
    const float* W_w     = (const float*)d_in[8];
    const float* b_w     = (const float*)d_in[9];
    const float* A_log   = (const float*)d_in[10];
    const float* Dv      = (const float*)d_in[11];
    const float* W_B     = (const float*)d_in[12];
    const float* b_B     = (const float*)d_in[13];
    const float* W_C     = (const float*)d_in[14];
    const float* b_C     = (const float*)d_in[15];
    const float* gamma   = (const float*)d_in[16];
    const float* beta    = (const float*)d_in[17];
    float* out = (float*)d_out;

    const int Nn = in_sizes[1];           // 16383

    float* ws    = (float*)d_ws;
    float* lw    = ws;                                      // 16384
    float* delta = lw + MPAD;                               // 16384*512 fp32
    float* Bm    = delta + (size_t)MPAD * 512;              // 16384*16
    float* Cm    = Bm + (size_t)MPAD * 16;                  // 16384*16
    unsigned short* s_bf  = (unsigned short*)(Cm + (size_t)MPAD * 16);  // 16384*512
    unsigned short* x_bf  = s_bf + (size_t)MPAD * 512;      // 16384*512
    unsigned short* Win_bf = x_bf + (size_t)MPAD * 512;     // 512*512
    unsigned short* Wd_bf  = Win_bf + 512 * 512;            // 640*512 (delta + B + C + pad)
    float* As_tab  = (float*)(Wd_bf + 640 * 512);           // 512
    int*   fast_tab = (int*)(As_tab + 512);                 // 512

    prep_kernel<<<MPAD + 1024 + 128 + 2, 256, 0, stream>>>(
        s_in, w, W_in, W_delta, W_B, W_C, A_log,
        s_bf, lw, Win_bf, Wd_bf, As_tab, fast_tab, Nn);

    dim3 g1(4, 128);   // 128-col x 128-row tiles -> 512 blocks
    gemm_mfma<<<g1, 256, 0, stream>>>(s_bf, Win_bf, nullptr, x_bf,
                                      b_in, lw, W_in + 512, 513, nullptr,
                                      nullptr, nullptr, nullptr, nullptr, 0);
    dim3 g2(5, 128);   // 5th col tile = B/C columns
    gemm_mfma<<<g2, 256, 0, stream>>>(x_bf, Wd_bf, delta, nullptr,
                                      b_delta, lw, W_w, 1, b_w,
                                      b_B, b_C, Bm, Cm, 1);

    scan_fused<<<2 * N_CKPT + CKPT_BASE, 512, 0, stream>>>(
        x_bf, delta, Bm, Cm, A_log, Dv, gamma, beta, As_tab, fast_tab, out);
}